// Round 2
// baseline (1033.146 us; speedup 1.0000x reference)
//
#include <hip/hip_runtime.h>
#include <hip/hip_bf16.h>
#include <math.h>

#define NNODES 100000
#define NEDGES 1600000
#define INC    256
#define HH     4
#define CC     64
#define HC     256            // H*C
#define SLOPE  0.2f

// ---------------------------------------------------------------------------
// K0: init out with bias (head-mean target), zero softmax denominators
// ---------------------------------------------------------------------------
__global__ void k_init(float* __restrict__ out, const float* __restrict__ bias,
                       float* __restrict__ denom) {
    int idx = blockIdx.x * blockDim.x + threadIdx.x;
    if (idx < NNODES * CC) out[idx] = bias[idx & (CC - 1)];
    if (idx < NNODES * HH) denom[idx] = 0.f;
}

// ---------------------------------------------------------------------------
// K1: h = x @ W    [N,256] @ [256,256] -> [N,256]
// 16 rows per block, 256 threads (one output column each), W streamed from L2.
// ---------------------------------------------------------------------------
__global__ __launch_bounds__(256) void k_gemm(const float* __restrict__ x,
                                              const float* __restrict__ W,
                                              float* __restrict__ h) {
    __shared__ float xs[16][INC];
    const int tid = threadIdx.x;
    const long row0 = (long)blockIdx.x * 16;

    #pragma unroll
    for (int r = 0; r < 16; ++r)
        xs[r][tid] = x[(row0 + r) * INC + tid];
    __syncthreads();

    float acc[16];
    #pragma unroll
    for (int r = 0; r < 16; ++r) acc[r] = 0.f;

    #pragma unroll 4
    for (int k = 0; k < INC; ++k) {
        float wk = W[k * HC + tid];          // coalesced across threads, L2-hot
        #pragma unroll
        for (int r = 0; r < 16; ++r) acc[r] += xs[r][k] * wk;  // LDS broadcast
    }

    #pragma unroll
    for (int r = 0; r < 16; ++r)
        h[(row0 + r) * HC + tid] = acc[r];
}

// ---------------------------------------------------------------------------
// K2: per-node attention logits a_src[n,h], a_dst[n,h]
// one node per block; wave w (lanes 0..63) handles head w
// ---------------------------------------------------------------------------
__global__ __launch_bounds__(256) void k_logits(const float* __restrict__ h,
                                                const float* __restrict__ att_src,
                                                const float* __restrict__ att_dst,
                                                float* __restrict__ a_src,
                                                float* __restrict__ a_dst) {
    const int n    = blockIdx.x;
    const int tid  = threadIdx.x;       // = head*64 + c
    const int head = tid >> 6;
    const int lane = tid & 63;

    float hv = h[(long)n * HC + tid];
    float s  = hv * att_src[tid];
    float d  = hv * att_dst[tid];
    #pragma unroll
    for (int off = 32; off > 0; off >>= 1) {
        s += __shfl_down(s, off, 64);
        d += __shfl_down(d, off, 64);
    }
    if (lane == 0) {
        a_src[n * HH + head] = s;
        a_dst[n * HH + head] = d;
    }
}

// ---------------------------------------------------------------------------
// K3: softmax denominators (no max-subtraction: logits bounded ~|8|, f32 safe)
// one edge per thread; self-loops are edges e >= NEDGES
// edge_index arrives as int32 (harness converts all integer inputs to int)
// ---------------------------------------------------------------------------
__global__ void k_denom(const int* __restrict__ ei,
                        const float* __restrict__ a_src,
                        const float* __restrict__ a_dst,
                        float* __restrict__ denom) {
    const long ETOT = (long)NEDGES + NNODES;
    long e = (long)blockIdx.x * blockDim.x + threadIdx.x;
    if (e >= ETOT) return;
    int src, dst;
    if (e < NEDGES) { src = ei[e]; dst = ei[NEDGES + e]; }
    else            { src = dst = (int)(e - NEDGES); }
    #pragma unroll
    for (int hd = 0; hd < HH; ++hd) {
        float a = a_src[src * HH + hd] + a_dst[dst * HH + hd];
        a = a > 0.f ? a : SLOPE * a;
        atomicAdd(&denom[dst * HH + hd], __expf(a));
    }
}

// ---------------------------------------------------------------------------
// K4: aggregation. One wave per edge. Lane = output channel c.
// Sums all 4 heads in-register -> a single atomicAdd per (edge, c).
// Head-mean (0.25f) folded in; bias already in out from k_init.
// ---------------------------------------------------------------------------
__global__ __launch_bounds__(256) void k_agg(const int* __restrict__ ei,
                                             const float* __restrict__ a_src,
                                             const float* __restrict__ a_dst,
                                             const float* __restrict__ denom,
                                             const float* __restrict__ h,
                                             float* __restrict__ out) {
    const long ETOT = (long)NEDGES + NNODES;
    long wave = ((long)blockIdx.x * blockDim.x + threadIdx.x) >> 6;
    const int lane = threadIdx.x & 63;
    if (wave >= ETOT) return;

    int src, dst;
    if (wave < NEDGES) { src = ei[wave]; dst = ei[NEDGES + wave]; }
    else               { src = dst = (int)(wave - NEDGES); }

    float acc = 0.f;
    #pragma unroll
    for (int hd = 0; hd < HH; ++hd) {
        float a = a_src[src * HH + hd] + a_dst[dst * HH + hd];
        a = a > 0.f ? a : SLOPE * a;
        float coef = __expf(a) / (denom[dst * HH + hd] + 1e-16f);
        acc += h[(long)src * HC + hd * CC + lane] * coef;   // coalesced 256B/head
    }
    atomicAdd(&out[(long)dst * CC + lane], 0.25f * acc);
}

// ---------------------------------------------------------------------------
extern "C" void kernel_launch(void* const* d_in, const int* in_sizes, int n_in,
                              void* d_out, int out_size, void* d_ws, size_t ws_size,
                              hipStream_t stream) {
    const float* x       = (const float*)d_in[0];
    const int*   ei      = (const int*)d_in[1];      // int32 per harness contract
    const float* W       = (const float*)d_in[2];
    const float* att_src = (const float*)d_in[3];
    const float* att_dst = (const float*)d_in[4];
    const float* bias    = (const float*)d_in[5];
    float* out = (float*)d_out;

    char* ws = (char*)d_ws;
    float* h     = (float*)ws;                                 // 102.4 MB
    float* a_src = (float*)(ws + (size_t)NNODES * HC * 4);     // 1.6 MB
    float* a_dst = a_src + (size_t)NNODES * HH;                // 1.6 MB
    float* denom = a_dst + (size_t)NNODES * HH;                // 1.6 MB

    const long ETOT = (long)NEDGES + NNODES;

    k_init<<<(NNODES * CC + 255) / 256, 256, 0, stream>>>(out, bias, denom);
    k_gemm<<<NNODES / 16, 256, 0, stream>>>(x, W, h);
    k_logits<<<NNODES, 256, 0, stream>>>(h, att_src, att_dst, a_src, a_dst);
    k_denom<<<(int)((ETOT + 255) / 256), 256, 0, stream>>>(ei, a_src, a_dst, denom);
    k_agg<<<(int)((ETOT * 64 + 255) / 256), 256, 0, stream>>>(ei, a_src, a_dst, denom, h, out);
}

// Round 3
// 730.231 us; speedup vs baseline: 1.4148x; 1.4148x over previous
//
#include <hip/hip_runtime.h>
#include <math.h>

#define NNODES 100000
#define NEDGES 1600000
#define ETOT   (NEDGES + NNODES)
#define INC    256
#define HH     4
#define CC     64
#define HC     256
#define SLOPE  0.2f
#define DCAP   128                      // per-node LDS edge cap (max deg ~40 for Poisson(17))
#define NB     ((NNODES + 255) / 256)   // 391 scan blocks

// ---------------------------------------------------------------------------
// K1: fused h = x@W  +  per-node logits (wave w == head w, xor-shuffle reduce)
// ---------------------------------------------------------------------------
__global__ __launch_bounds__(256) void k_gemm_logits(
        const float* __restrict__ x, const float* __restrict__ W,
        const float* __restrict__ att_src, const float* __restrict__ att_dst,
        float* __restrict__ h, float* __restrict__ a_src, float* __restrict__ a_dst) {
    __shared__ float xs[16][INC];
    const int tid = threadIdx.x;
    const long row0 = (long)blockIdx.x * 16;

    #pragma unroll
    for (int r = 0; r < 16; ++r)
        xs[r][tid] = x[(row0 + r) * INC + tid];
    __syncthreads();

    float acc[16];
    #pragma unroll
    for (int r = 0; r < 16; ++r) acc[r] = 0.f;

    #pragma unroll 4
    for (int k = 0; k < INC; ++k) {
        float wk = W[k * HC + tid];
        #pragma unroll
        for (int r = 0; r < 16; ++r) acc[r] += xs[r][k] * wk;
    }

    #pragma unroll
    for (int r = 0; r < 16; ++r)
        h[(row0 + r) * HC + tid] = acc[r];

    const float asv = att_src[tid], adv = att_dst[tid];
    const int head = tid >> 6, lane = tid & 63;
    #pragma unroll
    for (int r = 0; r < 16; ++r) {
        float s = acc[r] * asv, d = acc[r] * adv;
        #pragma unroll
        for (int o = 32; o > 0; o >>= 1) {
            s += __shfl_xor(s, o, 64);
            d += __shfl_xor(d, o, 64);
        }
        if (lane == 0) {
            a_src[(row0 + r) * HH + head] = s;
            a_dst[(row0 + r) * HH + head] = d;
        }
    }
}

// ---------------------------------------------------------------------------
// CSR build: zero -> count -> scan(3) -> scatter
// ---------------------------------------------------------------------------
__global__ void k_zero(int* __restrict__ deg) {
    int i = blockIdx.x * 256 + threadIdx.x;
    if (i < NNODES) deg[i] = 0;
}

__global__ void k_count(const int* __restrict__ ei, int* __restrict__ deg) {
    int e = blockIdx.x * 256 + threadIdx.x;
    if (e >= ETOT) return;
    int dst = (e < NEDGES) ? ei[NEDGES + e] : (e - NEDGES);
    atomicAdd(&deg[dst], 1);
}

__global__ void k_scan1(const int* __restrict__ deg, int* __restrict__ bsum) {
    __shared__ int s[256];
    int t = threadIdx.x, i = blockIdx.x * 256 + t;
    s[t] = (i < NNODES) ? deg[i] : 0;
    __syncthreads();
    for (int o = 128; o > 0; o >>= 1) {
        if (t < o) s[t] += s[t + o];
        __syncthreads();
    }
    if (t == 0) bsum[blockIdx.x] = s[0];
}

__global__ void k_scan2(const int* __restrict__ bsum, int* __restrict__ boff) {
    __shared__ int s[512];
    int t = threadIdx.x;
    int v = (t < NB) ? bsum[t] : 0;
    s[t] = v;
    __syncthreads();
    for (int o = 1; o < 512; o <<= 1) {
        int u = (t >= o) ? s[t - o] : 0;
        __syncthreads();
        s[t] += u;
        __syncthreads();
    }
    if (t < NB) boff[t] = s[t] - v;   // exclusive
}

__global__ void k_scan3(const int* __restrict__ deg, const int* __restrict__ boff,
                        int* __restrict__ rowptr, int* __restrict__ cursor) {
    __shared__ int s[256];
    int t = threadIdx.x, i = blockIdx.x * 256 + t;
    int v = (i < NNODES) ? deg[i] : 0;
    s[t] = v;
    __syncthreads();
    for (int o = 1; o < 256; o <<= 1) {
        int u = (t >= o) ? s[t - o] : 0;
        __syncthreads();
        s[t] += u;
        __syncthreads();
    }
    if (i < NNODES) {
        int r = boff[blockIdx.x] + s[t] - v;
        rowptr[i] = r;
        cursor[i] = r;
    }
}

__global__ void k_scatter(const int* __restrict__ ei, int* __restrict__ cursor,
                          int* __restrict__ es) {
    int e = blockIdx.x * 256 + threadIdx.x;
    if (e >= ETOT) return;
    int src, dst;
    if (e < NEDGES) { src = ei[e]; dst = ei[NEDGES + e]; }
    else            { src = dst = e - NEDGES; }
    int pos = atomicAdd(&cursor[dst], 1);
    es[pos] = src;
}

// ---------------------------------------------------------------------------
// K2: fused segment-softmax + aggregation. One wave per dst node.
// Pass A: lanes = 16 edges x 4 heads -> exp into LDS + shuffle-reduced denom.
// Pass B: lane = channel; LDS-broadcast coefs, coalesced h[src] gather, one store.
// No float atomics anywhere.
// ---------------------------------------------------------------------------
__global__ __launch_bounds__(256) void k_agg(
        const int* __restrict__ es, const int* __restrict__ rowptr,
        const int* __restrict__ cursor,            // cursor[n] == rowptr[n]+deg[n]
        const float* __restrict__ a_src, const float* __restrict__ a_dst,
        const float* __restrict__ h, const float* __restrict__ bias,
        float* __restrict__ out) {
    __shared__ float pex[4][DCAP * HH];
    __shared__ int   ssrc[4][DCAP];
    const int w = threadIdx.x >> 6, lane = threadIdx.x & 63;
    const int n = blockIdx.x * 4 + w;
    const int row0 = rowptr[n];
    const int d = cursor[n] - row0;
    const int hd = lane & 3, esub = lane >> 2;

    const float adst = a_dst[n * HH + hd];
    float dsum = 0.f;
    for (int base = 0; base < d; base += 16) {
        int el = base + esub;
        float ex = 0.f;
        if (el < d) {
            int s = es[row0 + el];
            float a = a_src[s * HH + hd] + adst;
            a = a > 0.f ? a : SLOPE * a;
            ex = __expf(a);
            if (el < DCAP) {
                pex[w][el * HH + hd] = ex;
                if (hd == 0) ssrc[w][el] = s;
            }
        }
        dsum += ex;
    }
    dsum += __shfl_xor(dsum, 4, 64);
    dsum += __shfl_xor(dsum, 8, 64);
    dsum += __shfl_xor(dsum, 16, 64);
    dsum += __shfl_xor(dsum, 32, 64);
    float rinv = 1.0f / (dsum + 1e-16f);
    float r0 = __shfl(rinv, 0, 64), r1 = __shfl(rinv, 1, 64);
    float r2 = __shfl(rinv, 2, 64), r3 = __shfl(rinv, 3, 64);
    __syncthreads();

    float accv = 0.f;
    const float* pexw = pex[w];
    const int* sw = ssrc[w];
    const int dcl = d < DCAP ? d : DCAP;
    for (int el = 0; el < dcl; ++el) {
        int s = sw[el];
        const float* hp = h + (size_t)s * HC + lane;
        float c0 = pexw[el * 4 + 0] * r0;
        float c1 = pexw[el * 4 + 1] * r1;
        float c2 = pexw[el * 4 + 2] * r2;
        float c3 = pexw[el * 4 + 3] * r3;
        accv += hp[0] * c0 + hp[64] * c1 + hp[128] * c2 + hp[192] * c3;
    }
    for (int el = DCAP; el < d; ++el) {   // overflow path (statistically never)
        int s = es[row0 + el];
        #pragma unroll
        for (int q = 0; q < 4; ++q) {
            float a = a_src[s * HH + q] + a_dst[n * HH + q];
            a = a > 0.f ? a : SLOPE * a;
            float rq = (q == 0) ? r0 : (q == 1) ? r1 : (q == 2) ? r2 : r3;
            accv += h[(size_t)s * HC + q * CC + lane] * (__expf(a) * rq);
        }
    }
    out[n * CC + lane] = 0.25f * accv + bias[lane];
}

// ---------------------------------------------------------------------------
extern "C" void kernel_launch(void* const* d_in, const int* in_sizes, int n_in,
                              void* d_out, int out_size, void* d_ws, size_t ws_size,
                              hipStream_t stream) {
    const float* x       = (const float*)d_in[0];
    const int*   ei      = (const int*)d_in[1];      // int32 per harness contract
    const float* W       = (const float*)d_in[2];
    const float* att_src = (const float*)d_in[3];
    const float* att_dst = (const float*)d_in[4];
    const float* bias    = (const float*)d_in[5];
    float* out = (float*)d_out;

    char* ws = (char*)d_ws;
    float* h      = (float*)ws;                                  // 102.4 MB
    float* a_src  = (float*)(ws + (size_t)NNODES * HC * 4);      // 1.6 MB
    float* a_dst  = a_src + (size_t)NNODES * HH;                 // 1.6 MB
    int*   deg    = (int*)(a_dst + (size_t)NNODES * HH);         // 400 KB
    int*   rowptr = deg + NNODES;                                // 400 KB
    int*   cursor = rowptr + NNODES;                             // 400 KB
    int*   bsum   = cursor + NNODES;                             // ~1.6 KB
    int*   boff   = bsum + NB;                                   // ~1.6 KB
    int*   es     = boff + NB;                                   // 6.8 MB

    const int egrid = (ETOT + 255) / 256;

    k_zero<<<NB, 256, 0, stream>>>(deg);
    k_gemm_logits<<<NNODES / 16, 256, 0, stream>>>(x, W, att_src, att_dst,
                                                   h, a_src, a_dst);
    k_count<<<egrid, 256, 0, stream>>>(ei, deg);
    k_scan1<<<NB, 256, 0, stream>>>(deg, bsum);
    k_scan2<<<1, 512, 0, stream>>>(bsum, boff);
    k_scan3<<<NB, 256, 0, stream>>>(deg, boff, rowptr, cursor);
    k_scatter<<<egrid, 256, 0, stream>>>(ei, cursor, es);
    k_agg<<<NNODES / 4, 256, 0, stream>>>(es, rowptr, cursor, a_src, a_dst,
                                          h, bias, out);
}

// Round 4
// 527.402 us; speedup vs baseline: 1.9589x; 1.3846x over previous
//
#include <hip/hip_runtime.h>
#include <hip/hip_bf16.h>
#include <math.h>

#define NNODES 100000
#define NEDGES 1600000
#define ETOT   (NEDGES + NNODES)
#define INC    256
#define HH     4
#define CC     64
#define HC     256
#define SLOPE  0.2f
#define DCAP   128                      // per-node LDS edge cap (max deg ~40 for Poisson(17))
#define NB     ((NNODES + 255) / 256)   // 391 scan blocks

typedef __attribute__((ext_vector_type(8))) short short8;  // 8 bf16 = 4 VGPR
typedef __attribute__((ext_vector_type(4))) float f32x4;

__device__ __forceinline__ ushort f2b(float f) {
    __hip_bfloat16 b = __float2bfloat16(f);      // RNE
    return *reinterpret_cast<ushort*>(&b);
}

// ---------------------------------------------------------------------------
// K_wt: Wt[n][k] = bf16(W[k][n])  (256x256, tiny, L2-resident afterwards)
// ---------------------------------------------------------------------------
__global__ void k_wt(const float* __restrict__ W, ushort* __restrict__ Wt) {
    int n = blockIdx.x, k = threadIdx.x;
    Wt[n * INC + k] = f2b(W[k * HC + n]);
}

// ---------------------------------------------------------------------------
// K1: MFMA GEMM h = x@W (bf16 inputs, f32 acc) + fused per-node logits.
// Block = 64 rows x 256 cols, 4 waves; wave w covers cols [64w,64w+64) = head w.
// x-tile staged once to LDS as bf16 with XOR swizzle; single barrier.
// ---------------------------------------------------------------------------
__global__ __launch_bounds__(256) void k_gemm_logits(
        const float* __restrict__ x, const ushort* __restrict__ Wt,
        const float* __restrict__ att_src, const float* __restrict__ att_dst,
        float* __restrict__ h, float* __restrict__ a_src, float* __restrict__ a_dst) {
    __shared__ char xs[64 * 512];            // 64 rows x 256 bf16, swizzled
    const int tid  = threadIdx.x;
    const int w    = tid >> 6, lane = tid & 63;
    const int rsel = lane & 15, g = lane >> 4;     // g = k-group / row-group
    const long row0 = (long)blockIdx.x * 64;

    // ---- stage x -> bf16 LDS (2048 chunks of 16 B, 8 per thread) ----
    #pragma unroll
    for (int i = 0; i < 8; ++i) {
        int chunk = i * 256 + tid;
        int row = chunk >> 5;                 // 32 chunks (512 B) per row
        int kb  = (chunk & 31) * 16;          // byte offset in row
        long grow = row0 + row; if (grow > NNODES - 1) grow = NNODES - 1;
        const float* src = x + grow * INC + (kb >> 1);
        float4 f0 = *(const float4*)(src);
        float4 f1 = *(const float4*)(src + 4);
        union { uint4 u; ushort us[8]; } p;
        p.us[0] = f2b(f0.x); p.us[1] = f2b(f0.y); p.us[2] = f2b(f0.z); p.us[3] = f2b(f0.w);
        p.us[4] = f2b(f1.x); p.us[5] = f2b(f1.y); p.us[6] = f2b(f1.z); p.us[7] = f2b(f1.w);
        *(uint4*)(xs + row * 512 + (kb ^ ((row & 7) << 4))) = p.u;
    }
    __syncthreads();

    // ---- MFMA main loop: 8 K-steps of 32 ----
    f32x4 acc[4][4];
    #pragma unroll
    for (int fr = 0; fr < 4; ++fr)
        #pragma unroll
        for (int fc = 0; fc < 4; ++fc)
            acc[fr][fc] = (f32x4)0.f;

    const char* WtB = (const char*)Wt;
    #pragma unroll 2
    for (int k0 = 0; k0 < INC; k0 += 32) {
        const int kbase = k0 * 2 + g * 16;    // byte offset of this lane's 8 bf16
        short8 b[4], a[4];
        #pragma unroll
        for (int fc = 0; fc < 4; ++fc) {
            int n = w * 64 + fc * 16 + rsel;
            b[fc] = *(const short8*)(WtB + (size_t)n * 512 + kbase);   // L2-hot
        }
        #pragma unroll
        for (int fr = 0; fr < 4; ++fr) {
            int row = fr * 16 + rsel;
            a[fr] = *(const short8*)(xs + row * 512 + (kbase ^ ((row & 7) << 4)));
        }
        #pragma unroll
        for (int fr = 0; fr < 4; ++fr)
            #pragma unroll
            for (int fc = 0; fc < 4; ++fc)
                acc[fr][fc] = __builtin_amdgcn_mfma_f32_16x16x32_bf16(
                                  a[fr], b[fc], acc[fr][fc], 0, 0, 0);
    }

    // ---- epilogue 1: store h (f32). D-layout: row=(g*4+r), col=l&15 (m89) ----
    #pragma unroll
    for (int fr = 0; fr < 4; ++fr) {
        #pragma unroll
        for (int r = 0; r < 4; ++r) {
            long grow = row0 + fr * 16 + g * 4 + r;
            if (grow < NNODES) {
                float* hp = h + grow * HC + w * 64 + rsel;
                hp[0]  = acc[fr][0][r];
                hp[16] = acc[fr][1][r];
                hp[32] = acc[fr][2][r];
                hp[48] = acc[fr][3][r];
            }
        }
    }

    // ---- epilogue 2: logits. Wave w == head w; reduce over 16 col-lanes ----
    float asv[4], adv[4];
    #pragma unroll
    for (int fc = 0; fc < 4; ++fc) {
        asv[fc] = att_src[w * 64 + fc * 16 + rsel];
        adv[fc] = att_dst[w * 64 + fc * 16 + rsel];
    }
    #pragma unroll
    for (int fr = 0; fr < 4; ++fr) {
        #pragma unroll
        for (int r = 0; r < 4; ++r) {
            float s = 0.f, d = 0.f;
            #pragma unroll
            for (int fc = 0; fc < 4; ++fc) {
                s += acc[fr][fc][r] * asv[fc];
                d += acc[fr][fc][r] * adv[fc];
            }
            #pragma unroll
            for (int o = 1; o < 16; o <<= 1) {
                s += __shfl_xor(s, o, 64);
                d += __shfl_xor(d, o, 64);
            }
            long grow = row0 + fr * 16 + g * 4 + r;
            if (rsel == 0 && grow < NNODES) {
                a_src[grow * HH + w] = s;
                a_dst[grow * HH + w] = d;
            }
        }
    }
}

// ---------------------------------------------------------------------------
// CSR build: zero -> count -> scan(3) -> scatter
// ---------------------------------------------------------------------------
__global__ void k_zero(int* __restrict__ deg) {
    int i = blockIdx.x * 256 + threadIdx.x;
    if (i < NNODES) deg[i] = 0;
}

__global__ void k_count(const int* __restrict__ ei, int* __restrict__ deg) {
    int e = blockIdx.x * 256 + threadIdx.x;
    if (e >= ETOT) return;
    int dst = (e < NEDGES) ? ei[NEDGES + e] : (e - NEDGES);
    atomicAdd(&deg[dst], 1);
}

__global__ void k_scan1(const int* __restrict__ deg, int* __restrict__ bsum) {
    __shared__ int s[256];
    int t = threadIdx.x, i = blockIdx.x * 256 + t;
    s[t] = (i < NNODES) ? deg[i] : 0;
    __syncthreads();
    for (int o = 128; o > 0; o >>= 1) {
        if (t < o) s[t] += s[t + o];
        __syncthreads();
    }
    if (t == 0) bsum[blockIdx.x] = s[0];
}

__global__ void k_scan2(const int* __restrict__ bsum, int* __restrict__ boff) {
    __shared__ int s[512];
    int t = threadIdx.x;
    int v = (t < NB) ? bsum[t] : 0;
    s[t] = v;
    __syncthreads();
    for (int o = 1; o < 512; o <<= 1) {
        int u = (t >= o) ? s[t - o] : 0;
        __syncthreads();
        s[t] += u;
        __syncthreads();
    }
    if (t < NB) boff[t] = s[t] - v;   // exclusive
}

__global__ void k_scan3(const int* __restrict__ deg, const int* __restrict__ boff,
                        int* __restrict__ rowptr, int* __restrict__ cursor) {
    __shared__ int s[256];
    int t = threadIdx.x, i = blockIdx.x * 256 + t;
    int v = (i < NNODES) ? deg[i] : 0;
    s[t] = v;
    __syncthreads();
    for (int o = 1; o < 256; o <<= 1) {
        int u = (t >= o) ? s[t - o] : 0;
        __syncthreads();
        s[t] += u;
        __syncthreads();
    }
    if (i < NNODES) {
        int r = boff[blockIdx.x] + s[t] - v;
        rowptr[i] = r;
        cursor[i] = r;
    }
}

__global__ void k_scatter(const int* __restrict__ ei, int* __restrict__ cursor,
                          int* __restrict__ es) {
    int e = blockIdx.x * 256 + threadIdx.x;
    if (e >= ETOT) return;
    int src, dst;
    if (e < NEDGES) { src = ei[e]; dst = ei[NEDGES + e]; }
    else            { src = dst = e - NEDGES; }
    int pos = atomicAdd(&cursor[dst], 1);
    es[pos] = src;
}

// ---------------------------------------------------------------------------
// K2: fused segment-softmax + aggregation. One wave per dst node.
// ---------------------------------------------------------------------------
__global__ __launch_bounds__(256) void k_agg(
        const int* __restrict__ es, const int* __restrict__ rowptr,
        const int* __restrict__ cursor,            // cursor[n] == rowptr[n]+deg[n]
        const float* __restrict__ a_src, const float* __restrict__ a_dst,
        const float* __restrict__ h, const float* __restrict__ bias,
        float* __restrict__ out) {
    __shared__ float pex[4][DCAP * HH];
    __shared__ int   ssrc[4][DCAP];
    const int w = threadIdx.x >> 6, lane = threadIdx.x & 63;
    const int n = blockIdx.x * 4 + w;
    const int row0 = rowptr[n];
    const int d = cursor[n] - row0;
    const int hd = lane & 3, esub = lane >> 2;

    const float adst = a_dst[n * HH + hd];
    float dsum = 0.f;
    for (int base = 0; base < d; base += 16) {
        int el = base + esub;
        float ex = 0.f;
        if (el < d) {
            int s = es[row0 + el];
            float a = a_src[s * HH + hd] + adst;
            a = a > 0.f ? a : SLOPE * a;
            ex = __expf(a);
            if (el < DCAP) {
                pex[w][el * HH + hd] = ex;
                if (hd == 0) ssrc[w][el] = s;
            }
        }
        dsum += ex;
    }
    dsum += __shfl_xor(dsum, 4, 64);
    dsum += __shfl_xor(dsum, 8, 64);
    dsum += __shfl_xor(dsum, 16, 64);
    dsum += __shfl_xor(dsum, 32, 64);
    float rinv = 1.0f / (dsum + 1e-16f);
    float r0 = __shfl(rinv, 0, 64), r1 = __shfl(rinv, 1, 64);
    float r2 = __shfl(rinv, 2, 64), r3 = __shfl(rinv, 3, 64);
    __syncthreads();

    float accv = 0.f;
    const float* pexw = pex[w];
    const int* sw = ssrc[w];
    const int dcl = d < DCAP ? d : DCAP;
    for (int el = 0; el < dcl; ++el) {
        int s = sw[el];
        const float* hp = h + (size_t)s * HC + lane;
        float c0 = pexw[el * 4 + 0] * r0;
        float c1 = pexw[el * 4 + 1] * r1;
        float c2 = pexw[el * 4 + 2] * r2;
        float c3 = pexw[el * 4 + 3] * r3;
        accv += hp[0] * c0 + hp[64] * c1 + hp[128] * c2 + hp[192] * c3;
    }
    for (int el = DCAP; el < d; ++el) {   // overflow path (statistically never)
        int s = es[row0 + el];
        #pragma unroll
        for (int q = 0; q < 4; ++q) {
            float a = a_src[s * HH + q] + a_dst[n * HH + q];
            a = a > 0.f ? a : SLOPE * a;
            float rq = (q == 0) ? r0 : (q == 1) ? r1 : (q == 2) ? r2 : r3;
            accv += h[(size_t)s * HC + q * CC + lane] * (__expf(a) * rq);
        }
    }
    out[n * CC + lane] = 0.25f * accv + bias[lane];
}

// ---------------------------------------------------------------------------
extern "C" void kernel_launch(void* const* d_in, const int* in_sizes, int n_in,
                              void* d_out, int out_size, void* d_ws, size_t ws_size,
                              hipStream_t stream) {
    const float* x       = (const float*)d_in[0];
    const int*   ei      = (const int*)d_in[1];      // int32 per harness contract
    const float* W       = (const float*)d_in[2];
    const float* att_src = (const float*)d_in[3];
    const float* att_dst = (const float*)d_in[4];
    const float* bias    = (const float*)d_in[5];
    float* out = (float*)d_out;

    char* ws = (char*)d_ws;
    float* h      = (float*)ws;                                  // 102.4 MB
    float* a_src  = (float*)(ws + (size_t)NNODES * HC * 4);      // 1.6 MB
    float* a_dst  = a_src + (size_t)NNODES * HH;                 // 1.6 MB
    int*   deg    = (int*)(a_dst + (size_t)NNODES * HH);         // 400 KB
    int*   rowptr = deg + NNODES;                                // 400 KB
    int*   cursor = rowptr + NNODES;                             // 400 KB
    int*   bsum   = cursor + NNODES;                             // ~1.6 KB
    int*   boff   = bsum + NB;                                   // ~1.6 KB
    int*   es     = boff + NB;                                   // 6.8 MB
    ushort* Wt    = (ushort*)(es + ETOT);                        // 128 KB

    const int egrid = (ETOT + 255) / 256;

    k_wt<<<HC, INC, 0, stream>>>(W, Wt);
    k_zero<<<NB, 256, 0, stream>>>(deg);
    k_gemm_logits<<<(NNODES + 63) / 64, 256, 0, stream>>>(x, Wt, att_src, att_dst,
                                                          h, a_src, a_dst);
    k_count<<<egrid, 256, 0, stream>>>(ei, deg);
    k_scan1<<<NB, 256, 0, stream>>>(deg, bsum);
    k_scan2<<<1, 512, 0, stream>>>(bsum, boff);
    k_scan3<<<NB, 256, 0, stream>>>(deg, boff, rowptr, cursor);
    k_scatter<<<egrid, 256, 0, stream>>>(ei, cursor, es);
    k_agg<<<NNODES / 4, 256, 0, stream>>>(es, rowptr, cursor, a_src, a_dst,
                                          h, bias, out);
}

// Round 5
// 410.600 us; speedup vs baseline: 2.5162x; 1.2845x over previous
//
#include <hip/hip_runtime.h>
#include <hip/hip_bf16.h>
#include <math.h>

#define NNODES 100000
#define NEDGES 1600000
#define ETOT   (NEDGES + NNODES)
#define INC    256
#define HH     4
#define CC     64
#define HC     256
#define SLOPE  0.2f
#define DCAP   128                      // per-node LDS edge cap (avg deg ~17)
#define NB     ((NNODES + 255) / 256)   // 391 scan blocks

typedef __attribute__((ext_vector_type(8))) short short8;  // 8 bf16 = 4 VGPR
typedef __attribute__((ext_vector_type(4))) float f32x4;

__device__ __forceinline__ ushort f2b(float f) {
    __hip_bfloat16 b = __float2bfloat16(f);      // RNE
    return *reinterpret_cast<ushort*>(&b);
}
__device__ __forceinline__ float blo(uint u) { return __uint_as_float(u << 16); }
__device__ __forceinline__ float bhi(uint u) { return __uint_as_float(u & 0xffff0000u); }

// ---------------------------------------------------------------------------
// K_prep: Wt[n][k] = bf16(W[k][n]) ; deg[i] = 1 (self-loop pre-counted)
// ---------------------------------------------------------------------------
__global__ void k_prep(const float* __restrict__ W, ushort* __restrict__ Wt,
                       int* __restrict__ deg) {
    int i = blockIdx.x * 256 + threadIdx.x;
    if (i < NNODES) deg[i] = 1;
    if (i < HC * INC) {
        int n = i >> 8, k = i & 255;
        Wt[n * INC + k] = f2b(W[k * HC + n]);
    }
}

// ---------------------------------------------------------------------------
// K1: MFMA GEMM h = x@W (bf16 in, f32 acc) + fused logits; h stored as bf16.
// Block = 64 rows x 256 cols, 4 waves; wave w covers cols [64w,64w+64) = head w.
// ---------------------------------------------------------------------------
__global__ __launch_bounds__(256) void k_gemm_logits(
        const float* __restrict__ x, const ushort* __restrict__ Wt,
        const float* __restrict__ att_src, const float* __restrict__ att_dst,
        ushort* __restrict__ hb, float* __restrict__ a_src, float* __restrict__ a_dst) {
    __shared__ char xs[64 * 512];            // 64 rows x 256 bf16, swizzled
    const int tid  = threadIdx.x;
    const int w    = tid >> 6, lane = tid & 63;
    const int rsel = lane & 15, g = lane >> 4;
    const long row0 = (long)blockIdx.x * 64;

    // ---- stage x -> bf16 LDS (2048 chunks of 16 B, 8 per thread) ----
    #pragma unroll
    for (int i = 0; i < 8; ++i) {
        int chunk = i * 256 + tid;
        int row = chunk >> 5;
        int kb  = (chunk & 31) * 16;
        long grow = row0 + row; if (grow > NNODES - 1) grow = NNODES - 1;
        const float* src = x + grow * INC + (kb >> 1);
        float4 f0 = *(const float4*)(src);
        float4 f1 = *(const float4*)(src + 4);
        union { uint4 u; ushort us[8]; } p;
        p.us[0] = f2b(f0.x); p.us[1] = f2b(f0.y); p.us[2] = f2b(f0.z); p.us[3] = f2b(f0.w);
        p.us[4] = f2b(f1.x); p.us[5] = f2b(f1.y); p.us[6] = f2b(f1.z); p.us[7] = f2b(f1.w);
        *(uint4*)(xs + row * 512 + (kb ^ ((row & 7) << 4))) = p.u;
    }
    __syncthreads();

    // ---- MFMA main loop: 8 K-steps of 32 ----
    f32x4 acc[4][4];
    #pragma unroll
    for (int fr = 0; fr < 4; ++fr)
        #pragma unroll
        for (int fc = 0; fc < 4; ++fc)
            acc[fr][fc] = (f32x4)0.f;

    const char* WtB = (const char*)Wt;
    #pragma unroll 2
    for (int k0 = 0; k0 < INC; k0 += 32) {
        const int kbase = k0 * 2 + g * 16;
        short8 b[4], a[4];
        #pragma unroll
        for (int fc = 0; fc < 4; ++fc) {
            int n = w * 64 + fc * 16 + rsel;
            b[fc] = *(const short8*)(WtB + (size_t)n * 512 + kbase);
        }
        #pragma unroll
        for (int fr = 0; fr < 4; ++fr) {
            int row = fr * 16 + rsel;
            a[fr] = *(const short8*)(xs + row * 512 + (kbase ^ ((row & 7) << 4)));
        }
        #pragma unroll
        for (int fr = 0; fr < 4; ++fr)
            #pragma unroll
            for (int fc = 0; fc < 4; ++fc)
                acc[fr][fc] = __builtin_amdgcn_mfma_f32_16x16x32_bf16(
                                  a[fr], b[fc], acc[fr][fc], 0, 0, 0);
    }

    // ---- epilogue 1: store h as bf16. D-layout: row=(g*4+r), col=l&15 ----
    #pragma unroll
    for (int fr = 0; fr < 4; ++fr) {
        #pragma unroll
        for (int r = 0; r < 4; ++r) {
            long grow = row0 + fr * 16 + g * 4 + r;
            if (grow < NNODES) {
                ushort* hp = hb + grow * HC + w * 64 + rsel;
                hp[0]  = f2b(acc[fr][0][r]);
                hp[16] = f2b(acc[fr][1][r]);
                hp[32] = f2b(acc[fr][2][r]);
                hp[48] = f2b(acc[fr][3][r]);
            }
        }
    }

    // ---- epilogue 2: logits from f32 acc; wave w == head w ----
    float asv[4], adv[4];
    #pragma unroll
    for (int fc = 0; fc < 4; ++fc) {
        asv[fc] = att_src[w * 64 + fc * 16 + rsel];
        adv[fc] = att_dst[w * 64 + fc * 16 + rsel];
    }
    #pragma unroll
    for (int fr = 0; fr < 4; ++fr) {
        #pragma unroll
        for (int r = 0; r < 4; ++r) {
            float s = 0.f, d = 0.f;
            #pragma unroll
            for (int fc = 0; fc < 4; ++fc) {
                s += acc[fr][fc][r] * asv[fc];
                d += acc[fr][fc][r] * adv[fc];
            }
            #pragma unroll
            for (int o = 1; o < 16; o <<= 1) {
                s += __shfl_xor(s, o, 64);
                d += __shfl_xor(d, o, 64);
            }
            long grow = row0 + fr * 16 + g * 4 + r;
            if (rsel == 0 && grow < NNODES) {
                a_src[grow * HH + w] = s;
                a_dst[grow * HH + w] = d;
            }
        }
    }
}

// ---------------------------------------------------------------------------
// CSR build: count (int4) -> scan(3, self-loop pre-seeded) -> scatter (int4)
// ---------------------------------------------------------------------------
__global__ void k_count(const int* __restrict__ ei, int* __restrict__ deg) {
    int t = blockIdx.x * 256 + threadIdx.x;
    if (t >= NEDGES / 4) return;
    int4 d4 = ((const int4*)(ei + NEDGES))[t];
    atomicAdd(&deg[d4.x], 1);
    atomicAdd(&deg[d4.y], 1);
    atomicAdd(&deg[d4.z], 1);
    atomicAdd(&deg[d4.w], 1);
}

__global__ void k_scan1(const int* __restrict__ deg, int* __restrict__ bsum) {
    __shared__ int s[256];
    int t = threadIdx.x, i = blockIdx.x * 256 + t;
    s[t] = (i < NNODES) ? deg[i] : 0;
    __syncthreads();
    for (int o = 128; o > 0; o >>= 1) {
        if (t < o) s[t] += s[t + o];
        __syncthreads();
    }
    if (t == 0) bsum[blockIdx.x] = s[0];
}

__global__ void k_scan2(const int* __restrict__ bsum, int* __restrict__ boff) {
    __shared__ int s[512];
    int t = threadIdx.x;
    int v = (t < NB) ? bsum[t] : 0;
    s[t] = v;
    __syncthreads();
    for (int o = 1; o < 512; o <<= 1) {
        int u = (t >= o) ? s[t - o] : 0;
        __syncthreads();
        s[t] += u;
        __syncthreads();
    }
    if (t < NB) boff[t] = s[t] - v;   // exclusive
}

__global__ void k_scan3(const int* __restrict__ deg, const int* __restrict__ boff,
                        int* __restrict__ rowptr, int* __restrict__ cursor,
                        int* __restrict__ es) {
    __shared__ int s[256];
    int t = threadIdx.x, i = blockIdx.x * 256 + t;
    int v = (i < NNODES) ? deg[i] : 0;
    s[t] = v;
    __syncthreads();
    for (int o = 1; o < 256; o <<= 1) {
        int u = (t >= o) ? s[t - o] : 0;
        __syncthreads();
        s[t] += u;
        __syncthreads();
    }
    if (i < NNODES) {
        int r = boff[blockIdx.x] + s[t] - v;
        rowptr[i] = r;
        cursor[i] = r + 1;   // slot r holds the self-loop
        es[r] = i;
    }
}

__global__ void k_scatter(const int* __restrict__ ei, int* __restrict__ cursor,
                          int* __restrict__ es) {
    int t = blockIdx.x * 256 + threadIdx.x;
    if (t >= NEDGES / 4) return;
    int4 s4 = ((const int4*)ei)[t];
    int4 d4 = ((const int4*)(ei + NEDGES))[t];
    es[atomicAdd(&cursor[d4.x], 1)] = s4.x;
    es[atomicAdd(&cursor[d4.y], 1)] = s4.y;
    es[atomicAdd(&cursor[d4.z], 1)] = s4.z;
    es[atomicAdd(&cursor[d4.w], 1)] = s4.w;
}

// ---------------------------------------------------------------------------
// K2: fused segment-softmax + aggregation. One wave per dst node, bf16 h.
// Pass A: lanes = 16 edges x 4 heads -> exp -> LDS (permuted), denom reduce,
//         prescale coefs by 1/denom. Pass B: packed u32 gathers, half-split
//         heads {0,2}/{1,3}, cross-half shfl reduce, float2 store. No atomics.
// ---------------------------------------------------------------------------
__global__ __launch_bounds__(256) void k_agg(
        const int* __restrict__ es, const int* __restrict__ rowptr,
        const int* __restrict__ cursor,            // cursor[n] == rowptr[n]+deg[n]
        const float* __restrict__ a_src, const float* __restrict__ a_dst,
        const uint* __restrict__ h2,               // bf16 h, row = 128 u32
        const float* __restrict__ bias, float* __restrict__ out) {
    __shared__ float pex[4][DCAP * HH];   // [el][pos]: pos 0=h0, 1=h2, 2=h1, 3=h3
    __shared__ int   ssrc[4][DCAP];
    const int w = threadIdx.x >> 6, lane = threadIdx.x & 63;
    const int n = blockIdx.x * 4 + w;
    const int row0 = rowptr[n];
    const int d = cursor[n] - row0;
    const int hd = lane & 3, esub = lane >> 2;

    // ---- pass A: exp + denom ----
    const float adst = a_dst[n * HH + hd];
    const int pos = ((hd & 1) << 1) | (hd >> 1);   // 0->0, 1->2, 2->1, 3->3
    float dsum = 0.f;
    for (int base = 0; base < d; base += 16) {
        int el = base + esub;
        float ex = 0.f;
        if (el < d) {
            int s = es[row0 + el];
            float a = a_src[s * HH + hd] + adst;
            a = a > 0.f ? a : SLOPE * a;
            ex = __expf(a);
            if (el < DCAP) {
                pex[w][el * HH + pos] = ex;
                if (hd == 0) ssrc[w][el] = s;
            }
        }
        dsum += ex;
    }
    dsum += __shfl_xor(dsum, 4, 64);
    dsum += __shfl_xor(dsum, 8, 64);
    dsum += __shfl_xor(dsum, 16, 64);
    dsum += __shfl_xor(dsum, 32, 64);
    float rinv = 1.0f / (dsum + 1e-16f);
    float r0 = __shfl(rinv, 0, 64), r1 = __shfl(rinv, 1, 64);
    float r2 = __shfl(rinv, 2, 64), r3 = __shfl(rinv, 3, 64);

    // prescale coefs: entry idx has idx%4 == lane%4 == hd -> per-lane constant
    const int dcl = d < DCAP ? d : DCAP;
    const float rp = (hd == 0) ? r0 : (hd == 1) ? r2 : (hd == 2) ? r1 : r3;
    for (int idx = lane; idx < dcl * HH; idx += 64)
        pex[w][idx] *= rp;

    // ---- pass B: gather + accumulate ----
    const int half = lane >> 5;           // 0: heads 0,2 ; 1: heads 1,3
    const int m = lane & 31;
    float ax = 0.f, ay = 0.f;             // channels 2m, 2m+1
    const float* pexw = pex[w];
    const int* sw = ssrc[w];
    for (int el = 0; el < dcl; ++el) {
        int s = sw[el];
        const uint* hp = h2 + (size_t)s * 128;
        uint u0 = hp[half * 32 + m];          // head half
        uint u1 = hp[64 + half * 32 + m];     // head 2+half
        float2 cf = *(const float2*)(pexw + el * 4 + half * 2);
        ax += blo(u0) * cf.x + blo(u1) * cf.y;
        ay += bhi(u0) * cf.x + bhi(u1) * cf.y;
    }
    for (int el = dcl; el < d; ++el) {    // overflow path (statistically never)
        int s = es[row0 + el];
        float a0 = a_src[s * HH + half] + a_dst[n * HH + half];
        a0 = a0 > 0.f ? a0 : SLOPE * a0;
        float ca = __expf(a0) * (half == 0 ? r0 : r1);
        float a1 = a_src[s * HH + 2 + half] + a_dst[n * HH + 2 + half];
        a1 = a1 > 0.f ? a1 : SLOPE * a1;
        float cb = __expf(a1) * (half == 0 ? r2 : r3);
        const uint* hp = h2 + (size_t)s * 128;
        uint u0 = hp[half * 32 + m];
        uint u1 = hp[64 + half * 32 + m];
        ax += blo(u0) * ca + blo(u1) * cb;
        ay += bhi(u0) * ca + bhi(u1) * cb;
    }
    ax += __shfl_xor(ax, 32, 64);
    ay += __shfl_xor(ay, 32, 64);
    if (lane < 32) {
        float2 bi = *(const float2*)(bias + 2 * m);
        float2 o;
        o.x = 0.25f * ax + bi.x;
        o.y = 0.25f * ay + bi.y;
        *(float2*)(out + (size_t)n * CC + 2 * m) = o;
    }
}

// ---------------------------------------------------------------------------
extern "C" void kernel_launch(void* const* d_in, const int* in_sizes, int n_in,
                              void* d_out, int out_size, void* d_ws, size_t ws_size,
                              hipStream_t stream) {
    const float* x       = (const float*)d_in[0];
    const int*   ei      = (const int*)d_in[1];      // int32 per harness contract
    const float* W       = (const float*)d_in[2];
    const float* att_src = (const float*)d_in[3];
    const float* att_dst = (const float*)d_in[4];
    const float* bias    = (const float*)d_in[5];
    float* out = (float*)d_out;

    char* ws = (char*)d_ws;
    ushort* hb    = (ushort*)ws;                                 // 51.2 MB
    float* a_src  = (float*)(ws + (size_t)NNODES * HC * 2);      // 1.6 MB
    float* a_dst  = a_src + (size_t)NNODES * HH;                 // 1.6 MB
    int*   deg    = (int*)(a_dst + (size_t)NNODES * HH);         // 400 KB
    int*   rowptr = deg + NNODES;                                // 400 KB
    int*   cursor = rowptr + NNODES;                             // 400 KB
    int*   bsum   = cursor + NNODES;                             // ~1.6 KB
    int*   boff   = bsum + NB;                                   // ~1.6 KB
    int*   es     = boff + NB;                                   // 6.8 MB
    ushort* Wt    = (ushort*)(es + ETOT);                        // 128 KB

    k_prep<<<NB, 256, 0, stream>>>(W, Wt, deg);
    k_gemm_logits<<<(NNODES + 63) / 64, 256, 0, stream>>>(x, Wt, att_src, att_dst,
                                                          hb, a_src, a_dst);
    k_count<<<(NEDGES / 4 + 255) / 256, 256, 0, stream>>>(ei, deg);
    k_scan1<<<NB, 256, 0, stream>>>(deg, bsum);
    k_scan2<<<1, 512, 0, stream>>>(bsum, boff);
    k_scan3<<<NB, 256, 0, stream>>>(deg, boff, rowptr, cursor, es);
    k_scatter<<<(NEDGES / 4 + 255) / 256, 256, 0, stream>>>(ei, cursor, es);
    k_agg<<<NNODES / 4, 256, 0, stream>>>(es, rowptr, cursor, a_src, a_dst,
                                          (const uint*)hb, bias, out);
}

// Round 6
// 307.034 us; speedup vs baseline: 3.3649x; 1.3373x over previous
//
#include <hip/hip_runtime.h>
#include <hip/hip_bf16.h>
#include <math.h>

#define NNODES 100000
#define NEDGES 1600000
#define ETOT   (NEDGES + NNODES)
#define INC    256
#define HH     4
#define CC     64
#define HC     256
#define SLOPE  0.2f
#define DCAP   128                      // per-node LDS edge cap (avg deg ~17)
#define NB     ((NNODES + 255) / 256)   // 391 scan blocks

typedef __attribute__((ext_vector_type(8))) short short8;  // 8 bf16 = 4 VGPR
typedef __attribute__((ext_vector_type(4))) float f32x4;

__device__ __forceinline__ ushort f2b(float f) {
    __hip_bfloat16 b = __float2bfloat16(f);      // RNE
    return *reinterpret_cast<ushort*>(&b);
}
__device__ __forceinline__ float blo(uint u) { return __uint_as_float(u << 16); }
__device__ __forceinline__ float bhi(uint u) { return __uint_as_float(u & 0xffff0000u); }

// ---------------------------------------------------------------------------
// K_prep: Wt[n][k] = bf16(W[k][n]) ; deg[i] = 1 (self-loop pre-counted)
// ---------------------------------------------------------------------------
__global__ void k_prep(const float* __restrict__ W, ushort* __restrict__ Wt,
                       int* __restrict__ deg) {
    int i = blockIdx.x * 256 + threadIdx.x;
    if (i < NNODES) deg[i] = 1;
    if (i < HC * INC) {
        int n = i >> 8, k = i & 255;
        Wt[n * INC + k] = f2b(W[k * HC + n]);
    }
}

// ---------------------------------------------------------------------------
// K1: MFMA GEMM h = x@W (bf16 in, f32 acc) + fused logits; h stored as bf16.
// Block = 64 rows x 256 cols, 4 waves; wave w covers cols [64w,64w+64) = head w.
// ---------------------------------------------------------------------------
__global__ __launch_bounds__(256) void k_gemm_logits(
        const float* __restrict__ x, const ushort* __restrict__ Wt,
        const float* __restrict__ att_src, const float* __restrict__ att_dst,
        ushort* __restrict__ hb, float* __restrict__ a_src, float* __restrict__ a_dst) {
    __shared__ char xs[64 * 512];            // 64 rows x 256 bf16, swizzled
    const int tid  = threadIdx.x;
    const int w    = tid >> 6, lane = tid & 63;
    const int rsel = lane & 15, g = lane >> 4;
    const long row0 = (long)blockIdx.x * 64;

    // ---- stage x -> bf16 LDS (2048 chunks of 16 B, 8 per thread) ----
    #pragma unroll
    for (int i = 0; i < 8; ++i) {
        int chunk = i * 256 + tid;
        int row = chunk >> 5;
        int kb  = (chunk & 31) * 16;
        long grow = row0 + row; if (grow > NNODES - 1) grow = NNODES - 1;
        const float* src = x + grow * INC + (kb >> 1);
        float4 f0 = *(const float4*)(src);
        float4 f1 = *(const float4*)(src + 4);
        union { uint4 u; ushort us[8]; } p;
        p.us[0] = f2b(f0.x); p.us[1] = f2b(f0.y); p.us[2] = f2b(f0.z); p.us[3] = f2b(f0.w);
        p.us[4] = f2b(f1.x); p.us[5] = f2b(f1.y); p.us[6] = f2b(f1.z); p.us[7] = f2b(f1.w);
        *(uint4*)(xs + row * 512 + (kb ^ ((row & 7) << 4))) = p.u;
    }
    __syncthreads();

    // ---- MFMA main loop: 8 K-steps of 32 ----
    f32x4 acc[4][4];
    #pragma unroll
    for (int fr = 0; fr < 4; ++fr)
        #pragma unroll
        for (int fc = 0; fc < 4; ++fc)
            acc[fr][fc] = (f32x4)0.f;

    const char* WtB = (const char*)Wt;
    #pragma unroll 2
    for (int k0 = 0; k0 < INC; k0 += 32) {
        const int kbase = k0 * 2 + g * 16;
        short8 b[4], a[4];
        #pragma unroll
        for (int fc = 0; fc < 4; ++fc) {
            int n = w * 64 + fc * 16 + rsel;
            b[fc] = *(const short8*)(WtB + (size_t)n * 512 + kbase);
        }
        #pragma unroll
        for (int fr = 0; fr < 4; ++fr) {
            int row = fr * 16 + rsel;
            a[fr] = *(const short8*)(xs + row * 512 + (kbase ^ ((row & 7) << 4)));
        }
        #pragma unroll
        for (int fr = 0; fr < 4; ++fr)
            #pragma unroll
            for (int fc = 0; fc < 4; ++fc)
                acc[fr][fc] = __builtin_amdgcn_mfma_f32_16x16x32_bf16(
                                  a[fr], b[fc], acc[fr][fc], 0, 0, 0);
    }

    // ---- epilogue 1: store h as bf16. D-layout: row=(g*4+r), col=l&15 ----
    #pragma unroll
    for (int fr = 0; fr < 4; ++fr) {
        #pragma unroll
        for (int r = 0; r < 4; ++r) {
            long grow = row0 + fr * 16 + g * 4 + r;
            if (grow < NNODES) {
                ushort* hp = hb + grow * HC + w * 64 + rsel;
                hp[0]  = f2b(acc[fr][0][r]);
                hp[16] = f2b(acc[fr][1][r]);
                hp[32] = f2b(acc[fr][2][r]);
                hp[48] = f2b(acc[fr][3][r]);
            }
        }
    }

    // ---- epilogue 2: logits from f32 acc; wave w == head w ----
    float asv[4], adv[4];
    #pragma unroll
    for (int fc = 0; fc < 4; ++fc) {
        asv[fc] = att_src[w * 64 + fc * 16 + rsel];
        adv[fc] = att_dst[w * 64 + fc * 16 + rsel];
    }
    #pragma unroll
    for (int fr = 0; fr < 4; ++fr) {
        #pragma unroll
        for (int r = 0; r < 4; ++r) {
            float s = 0.f, d = 0.f;
            #pragma unroll
            for (int fc = 0; fc < 4; ++fc) {
                s += acc[fr][fc][r] * asv[fc];
                d += acc[fr][fc][r] * adv[fc];
            }
            #pragma unroll
            for (int o = 1; o < 16; o <<= 1) {
                s += __shfl_xor(s, o, 64);
                d += __shfl_xor(d, o, 64);
            }
            long grow = row0 + fr * 16 + g * 4 + r;
            if (rsel == 0 && grow < NNODES) {
                a_src[grow * HH + w] = s;
                a_dst[grow * HH + w] = d;
            }
        }
    }
}

// ---------------------------------------------------------------------------
// CSR build: count (int4, saves rank) -> scan(3) -> atomic-free scatter
// ---------------------------------------------------------------------------
__global__ void k_count(const int* __restrict__ ei, int* __restrict__ deg,
                        uchar4* __restrict__ rank) {
    int t = blockIdx.x * 256 + threadIdx.x;
    if (t >= NEDGES / 4) return;
    int4 d4 = ((const int4*)(ei + NEDGES))[t];
    uchar4 r;
    r.x = (unsigned char)atomicAdd(&deg[d4.x], 1);   // rank >= 1 (self-loop = 0)
    r.y = (unsigned char)atomicAdd(&deg[d4.y], 1);
    r.z = (unsigned char)atomicAdd(&deg[d4.z], 1);
    r.w = (unsigned char)atomicAdd(&deg[d4.w], 1);
    rank[t] = r;
}

__global__ void k_scan1(const int* __restrict__ deg, int* __restrict__ bsum) {
    __shared__ int s[256];
    int t = threadIdx.x, i = blockIdx.x * 256 + t;
    s[t] = (i < NNODES) ? deg[i] : 0;
    __syncthreads();
    for (int o = 128; o > 0; o >>= 1) {
        if (t < o) s[t] += s[t + o];
        __syncthreads();
    }
    if (t == 0) bsum[blockIdx.x] = s[0];
}

__global__ void k_scan2(const int* __restrict__ bsum, int* __restrict__ boff) {
    __shared__ int s[512];
    int t = threadIdx.x;
    int v = (t < NB) ? bsum[t] : 0;
    s[t] = v;
    __syncthreads();
    for (int o = 1; o < 512; o <<= 1) {
        int u = (t >= o) ? s[t - o] : 0;
        __syncthreads();
        s[t] += u;
        __syncthreads();
    }
    if (t < NB) boff[t] = s[t] - v;   // exclusive
}

__global__ void k_scan3(const int* __restrict__ deg, const int* __restrict__ boff,
                        int* __restrict__ rowptr, int* __restrict__ cursor,
                        int* __restrict__ es) {
    __shared__ int s[256];
    int t = threadIdx.x, i = blockIdx.x * 256 + t;
    int v = (i < NNODES) ? deg[i] : 0;
    s[t] = v;
    __syncthreads();
    for (int o = 1; o < 256; o <<= 1) {
        int u = (t >= o) ? s[t - o] : 0;
        __syncthreads();
        s[t] += u;
        __syncthreads();
    }
    if (i < NNODES) {
        int r = boff[blockIdx.x] + s[t] - v;
        rowptr[i] = r;
        cursor[i] = r + v;   // final row end (v = 1 + indeg)
        es[r] = i;           // self-loop occupies slot 0
    }
}

__global__ void k_scatter(const int* __restrict__ ei, const int* __restrict__ rowptr,
                          const uchar4* __restrict__ rank, int* __restrict__ es) {
    int t = blockIdx.x * 256 + threadIdx.x;
    if (t >= NEDGES / 4) return;
    int4 s4 = ((const int4*)ei)[t];
    int4 d4 = ((const int4*)(ei + NEDGES))[t];
    uchar4 r4 = rank[t];
    es[rowptr[d4.x] + r4.x] = s4.x;   // fire-and-forget scattered stores
    es[rowptr[d4.y] + r4.y] = s4.y;
    es[rowptr[d4.z] + r4.z] = s4.z;
    es[rowptr[d4.w] + r4.w] = s4.w;
}

// ---------------------------------------------------------------------------
// K2: fused segment-softmax + aggregation. One wave per dst node, bf16 h.
// ---------------------------------------------------------------------------
__global__ __launch_bounds__(256) void k_agg(
        const int* __restrict__ es, const int* __restrict__ rowptr,
        const int* __restrict__ cursor,            // cursor[n] == rowptr[n]+deg[n]
        const float* __restrict__ a_src, const float* __restrict__ a_dst,
        const uint* __restrict__ h2,               // bf16 h, row = 128 u32
        const float* __restrict__ bias, float* __restrict__ out) {
    __shared__ float pex[4][DCAP * HH];   // [el][pos]: pos 0=h0, 1=h2, 2=h1, 3=h3
    __shared__ int   ssrc[4][DCAP];
    const int w = threadIdx.x >> 6, lane = threadIdx.x & 63;
    const int n = blockIdx.x * 4 + w;
    const int row0 = rowptr[n];
    const int d = cursor[n] - row0;
    const int hd = lane & 3, esub = lane >> 2;

    // ---- pass A: exp + denom ----
    const float adst = a_dst[n * HH + hd];
    const int pos = ((hd & 1) << 1) | (hd >> 1);   // 0->0, 1->2, 2->1, 3->3
    float dsum = 0.f;
    for (int base = 0; base < d; base += 16) {
        int el = base + esub;
        float ex = 0.f;
        if (el < d) {
            int s = es[row0 + el];
            float a = a_src[s * HH + hd] + adst;
            a = a > 0.f ? a : SLOPE * a;
            ex = __expf(a);
            if (el < DCAP) {
                pex[w][el * HH + pos] = ex;
                if (hd == 0) ssrc[w][el] = s;
            }
        }
        dsum += ex;
    }
    dsum += __shfl_xor(dsum, 4, 64);
    dsum += __shfl_xor(dsum, 8, 64);
    dsum += __shfl_xor(dsum, 16, 64);
    dsum += __shfl_xor(dsum, 32, 64);
    float rinv = 1.0f / (dsum + 1e-16f);
    float r0 = __shfl(rinv, 0, 64), r1 = __shfl(rinv, 1, 64);
    float r2 = __shfl(rinv, 2, 64), r3 = __shfl(rinv, 3, 64);

    // prescale coefs: entry idx has idx%4 == lane%4 == hd -> per-lane constant
    const int dcl = d < DCAP ? d : DCAP;
    const float rp = (hd == 0) ? r0 : (hd == 1) ? r2 : (hd == 2) ? r1 : r3;
    for (int idx = lane; idx < dcl * HH; idx += 64)
        pex[w][idx] *= rp;

    // ---- pass B: gather + accumulate ----
    const int half = lane >> 5;           // 0: heads 0,2 ; 1: heads 1,3
    const int m = lane & 31;
    float ax = 0.f, ay = 0.f;             // channels 2m, 2m+1
    const float* pexw = pex[w];
    const int* sw = ssrc[w];
    for (int el = 0; el < dcl; ++el) {
        int s = sw[el];
        const uint* hp = h2 + (size_t)s * 128;
        uint u0 = hp[half * 32 + m];          // head half
        uint u1 = hp[64 + half * 32 + m];     // head 2+half
        float2 cf = *(const float2*)(pexw + el * 4 + half * 2);
        ax += blo(u0) * cf.x + blo(u1) * cf.y;
        ay += bhi(u0) * cf.x + bhi(u1) * cf.y;
    }
    for (int el = dcl; el < d; ++el) {    // overflow path (statistically never)
        int s = es[row0 + el];
        float a0 = a_src[s * HH + half] + a_dst[n * HH + half];
        a0 = a0 > 0.f ? a0 : SLOPE * a0;
        float ca = __expf(a0) * (half == 0 ? r0 : r1);
        float a1 = a_src[s * HH + 2 + half] + a_dst[n * HH + 2 + half];
        a1 = a1 > 0.f ? a1 : SLOPE * a1;
        float cb = __expf(a1) * (half == 0 ? r2 : r3);
        const uint* hp = h2 + (size_t)s * 128;
        uint u0 = hp[half * 32 + m];
        uint u1 = hp[64 + half * 32 + m];
        ax += blo(u0) * ca + blo(u1) * cb;
        ay += bhi(u0) * ca + bhi(u1) * cb;
    }
    ax += __shfl_xor(ax, 32, 64);
    ay += __shfl_xor(ay, 32, 64);
    if (lane < 32) {
        float2 bi = *(const float2*)(bias + 2 * m);
        float2 o;
        o.x = 0.25f * ax + bi.x;
        o.y = 0.25f * ay + bi.y;
        *(float2*)(out + (size_t)n * CC + 2 * m) = o;
    }
}

// ---------------------------------------------------------------------------
extern "C" void kernel_launch(void* const* d_in, const int* in_sizes, int n_in,
                              void* d_out, int out_size, void* d_ws, size_t ws_size,
                              hipStream_t stream) {
    const float* x       = (const float*)d_in[0];
    const int*   ei      = (const int*)d_in[1];      // int32 per harness contract
    const float* W       = (const float*)d_in[2];
    const float* att_src = (const float*)d_in[3];
    const float* att_dst = (const float*)d_in[4];
    const float* bias    = (const float*)d_in[5];
    float* out = (float*)d_out;

    char* ws = (char*)d_ws;
    ushort* hb    = (ushort*)ws;                                 // 51.2 MB
    float* a_src  = (float*)(ws + (size_t)NNODES * HC * 2);      // 1.6 MB
    float* a_dst  = a_src + (size_t)NNODES * HH;                 // 1.6 MB
    int*   deg    = (int*)(a_dst + (size_t)NNODES * HH);         // 400 KB
    int*   rowptr = deg + NNODES;                                // 400 KB
    int*   cursor = rowptr + NNODES;                             // 400 KB
    int*   bsum   = cursor + NNODES;                             // ~1.6 KB
    int*   boff   = bsum + NB;                                   // ~1.6 KB
    int*   es     = boff + NB;                                   // 6.8 MB
    ushort* Wt    = (ushort*)(es + ETOT);                        // 128 KB
    uchar4* rank  = (uchar4*)(Wt + HC * INC);                    // 1.6 MB

    k_prep<<<NB, 256, 0, stream>>>(W, Wt, deg);
    k_gemm_logits<<<(NNODES + 63) / 64, 256, 0, stream>>>(x, Wt, att_src, att_dst,
                                                          hb, a_src, a_dst);
    k_count<<<(NEDGES / 4 + 255) / 256, 256, 0, stream>>>(ei, deg, rank);
    k_scan1<<<NB, 256, 0, stream>>>(deg, bsum);
    k_scan2<<<1, 512, 0, stream>>>(bsum, boff);
    k_scan3<<<NB, 256, 0, stream>>>(deg, boff, rowptr, cursor, es);
    k_scatter<<<(NEDGES / 4 + 255) / 256, 256, 0, stream>>>(ei, rowptr, rank, es);
    k_agg<<<NNODES / 4, 256, 0, stream>>>(es, rowptr, cursor, a_src, a_dst,
                                          (const uint*)hb, bias, out);
}

// Round 7
// 304.727 us; speedup vs baseline: 3.3904x; 1.0076x over previous
//
#include <hip/hip_runtime.h>
#include <hip/hip_bf16.h>
#include <math.h>

#define NNODES 100000
#define NEDGES 1600000
#define ETOT   (NEDGES + NNODES)
#define INC    256
#define HH     4
#define CC     64
#define HC     256
#define SLOPE  0.2f
#define DCAP   64                       // per-node LDS edge cap (max deg ~40)
#define NB     ((NNODES + 255) / 256)   // 391 scan blocks

typedef __attribute__((ext_vector_type(8))) short short8;  // 8 bf16 = 4 VGPR
typedef __attribute__((ext_vector_type(4))) float f32x4;

__device__ __forceinline__ ushort f2b(float f) {
    __hip_bfloat16 b = __float2bfloat16(f);      // RNE
    return *reinterpret_cast<ushort*>(&b);
}
__device__ __forceinline__ float blo(uint u) { return __uint_as_float(u << 16); }
__device__ __forceinline__ float bhi(uint u) { return __uint_as_float(u & 0xffff0000u); }

// ---------------------------------------------------------------------------
// K_prep: Wt[n][k] = bf16(W[k][n]) ; deg[i] = 1 (self-loop pre-counted)
// ---------------------------------------------------------------------------
__global__ void k_prep(const float* __restrict__ W, ushort* __restrict__ Wt,
                       int* __restrict__ deg) {
    int i = blockIdx.x * 256 + threadIdx.x;
    if (i < NNODES) deg[i] = 1;
    if (i < HC * INC) {
        int n = i >> 8, k = i & 255;
        Wt[n * INC + k] = f2b(W[k * HC + n]);
    }
}

// ---------------------------------------------------------------------------
// K1: MFMA GEMM h = x@W (bf16 in, f32 acc) + fused logits.
// h stored HEAD-INTERLEAVED: hb[n*256 + c*4 + head]  (8 B per channel).
// Block = 64 rows x 256 cols, 4 waves; wave w covers cols [64w,64w+64) = head w.
// ---------------------------------------------------------------------------
__global__ __launch_bounds__(256) void k_gemm_logits(
        const float* __restrict__ x, const ushort* __restrict__ Wt,
        const float* __restrict__ att_src, const float* __restrict__ att_dst,
        ushort* __restrict__ hb, float* __restrict__ a_src, float* __restrict__ a_dst) {
    __shared__ char xs[64 * 512];            // 64 rows x 256 bf16, swizzled
    const int tid  = threadIdx.x;
    const int w    = tid >> 6, lane = tid & 63;
    const int rsel = lane & 15, g = lane >> 4;
    const long row0 = (long)blockIdx.x * 64;

    // ---- stage x -> bf16 LDS (2048 chunks of 16 B, 8 per thread) ----
    #pragma unroll
    for (int i = 0; i < 8; ++i) {
        int chunk = i * 256 + tid;
        int row = chunk >> 5;
        int kb  = (chunk & 31) * 16;
        long grow = row0 + row; if (grow > NNODES - 1) grow = NNODES - 1;
        const float* src = x + grow * INC + (kb >> 1);
        float4 f0 = *(const float4*)(src);
        float4 f1 = *(const float4*)(src + 4);
        union { uint4 u; ushort us[8]; } p;
        p.us[0] = f2b(f0.x); p.us[1] = f2b(f0.y); p.us[2] = f2b(f0.z); p.us[3] = f2b(f0.w);
        p.us[4] = f2b(f1.x); p.us[5] = f2b(f1.y); p.us[6] = f2b(f1.z); p.us[7] = f2b(f1.w);
        *(uint4*)(xs + row * 512 + (kb ^ ((row & 7) << 4))) = p.u;
    }
    __syncthreads();

    // ---- MFMA main loop: 8 K-steps of 32 ----
    f32x4 acc[4][4];
    #pragma unroll
    for (int fr = 0; fr < 4; ++fr)
        #pragma unroll
        for (int fc = 0; fc < 4; ++fc)
            acc[fr][fc] = (f32x4)0.f;

    const char* WtB = (const char*)Wt;
    #pragma unroll 2
    for (int k0 = 0; k0 < INC; k0 += 32) {
        const int kbase = k0 * 2 + g * 16;
        short8 b[4], a[4];
        #pragma unroll
        for (int fc = 0; fc < 4; ++fc) {
            int n = w * 64 + fc * 16 + rsel;
            b[fc] = *(const short8*)(WtB + (size_t)n * 512 + kbase);
        }
        #pragma unroll
        for (int fr = 0; fr < 4; ++fr) {
            int row = fr * 16 + rsel;
            a[fr] = *(const short8*)(xs + row * 512 + (kbase ^ ((row & 7) << 4)));
        }
        #pragma unroll
        for (int fr = 0; fr < 4; ++fr)
            #pragma unroll
            for (int fc = 0; fc < 4; ++fc)
                acc[fr][fc] = __builtin_amdgcn_mfma_f32_16x16x32_bf16(
                                  a[fr], b[fc], acc[fr][fc], 0, 0, 0);
    }

    // ---- epilogue 1: store h head-interleaved. D row=(g*4+r), col=l&15 ----
    // channel c = fc*16 + rsel of head w  ->  hb[grow*256 + c*4 + w]
    #pragma unroll
    for (int fr = 0; fr < 4; ++fr) {
        #pragma unroll
        for (int r = 0; r < 4; ++r) {
            long grow = row0 + fr * 16 + g * 4 + r;
            if (grow < NNODES) {
                ushort* hp = hb + grow * HC + rsel * 4 + w;
                hp[0]   = f2b(acc[fr][0][r]);    // c = rsel
                hp[64]  = f2b(acc[fr][1][r]);    // c = 16 + rsel
                hp[128] = f2b(acc[fr][2][r]);    // c = 32 + rsel
                hp[192] = f2b(acc[fr][3][r]);    // c = 48 + rsel
            }
        }
    }

    // ---- epilogue 2: logits from f32 acc; wave w == head w ----
    float asv[4], adv[4];
    #pragma unroll
    for (int fc = 0; fc < 4; ++fc) {
        asv[fc] = att_src[w * 64 + fc * 16 + rsel];
        adv[fc] = att_dst[w * 64 + fc * 16 + rsel];
    }
    #pragma unroll
    for (int fr = 0; fr < 4; ++fr) {
        #pragma unroll
        for (int r = 0; r < 4; ++r) {
            float s = 0.f, d = 0.f;
            #pragma unroll
            for (int fc = 0; fc < 4; ++fc) {
                s += acc[fr][fc][r] * asv[fc];
                d += acc[fr][fc][r] * adv[fc];
            }
            #pragma unroll
            for (int o = 1; o < 16; o <<= 1) {
                s += __shfl_xor(s, o, 64);
                d += __shfl_xor(d, o, 64);
            }
            long grow = row0 + fr * 16 + g * 4 + r;
            if (rsel == 0 && grow < NNODES) {
                a_src[grow * HH + w] = s;
                a_dst[grow * HH + w] = d;
            }
        }
    }
}

// ---------------------------------------------------------------------------
// CSR build: count (int4, saves rank) -> scan(3) -> atomic-free scatter
// ---------------------------------------------------------------------------
__global__ void k_count(const int* __restrict__ ei, int* __restrict__ deg,
                        uchar4* __restrict__ rank) {
    int t = blockIdx.x * 256 + threadIdx.x;
    if (t >= NEDGES / 4) return;
    int4 d4 = ((const int4*)(ei + NEDGES))[t];
    uchar4 r;
    r.x = (unsigned char)atomicAdd(&deg[d4.x], 1);   // rank >= 1 (self-loop = 0)
    r.y = (unsigned char)atomicAdd(&deg[d4.y], 1);
    r.z = (unsigned char)atomicAdd(&deg[d4.z], 1);
    r.w = (unsigned char)atomicAdd(&deg[d4.w], 1);
    rank[t] = r;
}

__global__ void k_scan1(const int* __restrict__ deg, int* __restrict__ bsum) {
    __shared__ int s[256];
    int t = threadIdx.x, i = blockIdx.x * 256 + t;
    s[t] = (i < NNODES) ? deg[i] : 0;
    __syncthreads();
    for (int o = 128; o > 0; o >>= 1) {
        if (t < o) s[t] += s[t + o];
        __syncthreads();
    }
    if (t == 0) bsum[blockIdx.x] = s[0];
}

__global__ void k_scan2(const int* __restrict__ bsum, int* __restrict__ boff) {
    __shared__ int s[512];
    int t = threadIdx.x;
    int v = (t < NB) ? bsum[t] : 0;
    s[t] = v;
    __syncthreads();
    for (int o = 1; o < 512; o <<= 1) {
        int u = (t >= o) ? s[t - o] : 0;
        __syncthreads();
        s[t] += u;
        __syncthreads();
    }
    if (t < NB) boff[t] = s[t] - v;   // exclusive
}

__global__ void k_scan3(const int* __restrict__ deg, const int* __restrict__ boff,
                        int* __restrict__ rowptr, int* __restrict__ cursor,
                        int* __restrict__ es) {
    __shared__ int s[256];
    int t = threadIdx.x, i = blockIdx.x * 256 + t;
    int v = (i < NNODES) ? deg[i] : 0;
    s[t] = v;
    __syncthreads();
    for (int o = 1; o < 256; o <<= 1) {
        int u = (t >= o) ? s[t - o] : 0;
        __syncthreads();
        s[t] += u;
        __syncthreads();
    }
    if (i < NNODES) {
        int r = boff[blockIdx.x] + s[t] - v;
        rowptr[i] = r;
        cursor[i] = r + v;   // final row end (v = 1 + indeg)
        es[r] = i;           // self-loop occupies slot 0
    }
}

__global__ void k_scatter(const int* __restrict__ ei, const int* __restrict__ rowptr,
                          const uchar4* __restrict__ rank, int* __restrict__ es) {
    int t = blockIdx.x * 256 + threadIdx.x;
    if (t >= NEDGES / 4) return;
    int4 s4 = ((const int4*)ei)[t];
    int4 d4 = ((const int4*)(ei + NEDGES))[t];
    uchar4 r4 = rank[t];
    es[rowptr[d4.x] + r4.x] = s4.x;   // fire-and-forget scattered stores
    es[rowptr[d4.y] + r4.y] = s4.y;
    es[rowptr[d4.z] + r4.z] = s4.z;
    es[rowptr[d4.w] + r4.w] = s4.w;
}

// ---------------------------------------------------------------------------
// K2: fused segment-softmax + aggregation. One wave per dst node.
// h head-interleaved: lane = channel, ONE dwordx2 gather per edge per lane,
// broadcast ds_read_b128 of 4 prescaled coefs, 4 FMA. No cross-lane reduce.
// ---------------------------------------------------------------------------
__global__ __launch_bounds__(256) void k_agg(
        const int* __restrict__ es, const int* __restrict__ rowptr,
        const int* __restrict__ cursor,            // cursor[n] == rowptr[n]+deg[n]
        const float* __restrict__ a_src, const float* __restrict__ a_dst,
        const uint2* __restrict__ h2,              // packed: row = 64 uint2
        const float* __restrict__ bias, float* __restrict__ out) {
    __shared__ float pex[4][DCAP * HH];
    __shared__ int   ssrc[4][DCAP];
    const int w = threadIdx.x >> 6, lane = threadIdx.x & 63;
    const int n = blockIdx.x * 4 + w;
    const int row0 = rowptr[n];
    const int d = cursor[n] - row0;
    const int hd = lane & 3, esub = lane >> 2;

    // ---- pass A: exp + denom ----
    const float adst = a_dst[n * HH + hd];
    float dsum = 0.f;
    for (int base = 0; base < d; base += 16) {
        int el = base + esub;
        float ex = 0.f;
        if (el < d) {
            int s = es[row0 + el];
            float a = a_src[s * HH + hd] + adst;
            a = a > 0.f ? a : SLOPE * a;
            ex = __expf(a);
            if (el < DCAP) {
                pex[w][el * HH + hd] = ex;
                if (hd == 0) ssrc[w][el] = s;
            }
        }
        dsum += ex;
    }
    dsum += __shfl_xor(dsum, 4, 64);
    dsum += __shfl_xor(dsum, 8, 64);
    dsum += __shfl_xor(dsum, 16, 64);
    dsum += __shfl_xor(dsum, 32, 64);
    float rinv = 1.0f / (dsum + 1e-16f);
    float r0 = __shfl(rinv, 0, 64), r1 = __shfl(rinv, 1, 64);
    float r2 = __shfl(rinv, 2, 64), r3 = __shfl(rinv, 3, 64);

    // prescale coefs: entry idx has idx%4 == hd -> per-lane constant multiplier
    const int dcl = d < DCAP ? d : DCAP;
    const float rp = (hd == 0) ? r0 : (hd == 1) ? r1 : (hd == 2) ? r2 : r3;
    for (int idx = lane; idx < dcl * HH; idx += 64)
        pex[w][idx] *= rp;

    // ---- pass B: gather + accumulate; lane = channel ----
    float acc = 0.f;
    const float* pexw = pex[w];
    const int* sw = ssrc[w];
    #pragma unroll 4
    for (int el = 0; el < dcl; ++el) {
        int s = sw[el];
        uint2 u = h2[(size_t)s * 64 + lane];            // 8 B: heads 0..3 @ chan=lane
        f32x4 cf = *(const f32x4*)(pexw + el * 4);      // LDS broadcast, 16 B
        acc += blo(u.x) * cf[0] + bhi(u.x) * cf[1]
             + blo(u.y) * cf[2] + bhi(u.y) * cf[3];
    }
    for (int el = dcl; el < d; ++el) {    // overflow path (statistically never)
        int s = es[row0 + el];
        float c[4];
        #pragma unroll
        for (int q = 0; q < 4; ++q) {
            float a = a_src[s * HH + q] + a_dst[n * HH + q];
            a = a > 0.f ? a : SLOPE * a;
            float rq = (q == 0) ? r0 : (q == 1) ? r1 : (q == 2) ? r2 : r3;
            c[q] = __expf(a) * rq;
        }
        uint2 u = h2[(size_t)s * 64 + lane];
        acc += blo(u.x) * c[0] + bhi(u.x) * c[1]
             + blo(u.y) * c[2] + bhi(u.y) * c[3];
    }
    out[(size_t)n * CC + lane] = 0.25f * acc + bias[lane];
}

// ---------------------------------------------------------------------------
extern "C" void kernel_launch(void* const* d_in, const int* in_sizes, int n_in,
                              void* d_out, int out_size, void* d_ws, size_t ws_size,
                              hipStream_t stream) {
    const float* x       = (const float*)d_in[0];
    const int*   ei      = (const int*)d_in[1];      // int32 per harness contract
    const float* W       = (const float*)d_in[2];
    const float* att_src = (const float*)d_in[3];
    const float* att_dst = (const float*)d_in[4];
    const float* bias    = (const float*)d_in[5];
    float* out = (float*)d_out;

    char* ws = (char*)d_ws;
    ushort* hb    = (ushort*)ws;                                 // 51.2 MB
    float* a_src  = (float*)(ws + (size_t)NNODES * HC * 2);      // 1.6 MB
    float* a_dst  = a_src + (size_t)NNODES * HH;                 // 1.6 MB
    int*   deg    = (int*)(a_dst + (size_t)NNODES * HH);         // 400 KB
    int*   rowptr = deg + NNODES;                                // 400 KB
    int*   cursor = rowptr + NNODES;                             // 400 KB
    int*   bsum   = cursor + NNODES;                             // ~1.6 KB
    int*   boff   = bsum + NB;                                   // ~1.6 KB
    int*   es     = boff + NB;                                   // 6.8 MB
    ushort* Wt    = (ushort*)(es + ETOT);                        // 128 KB
    uchar4* rank  = (uchar4*)(Wt + HC * INC);                    // 1.6 MB

    k_prep<<<NB, 256, 0, stream>>>(W, Wt, deg);
    k_gemm_logits<<<(NNODES + 63) / 64, 256, 0, stream>>>(x, Wt, att_src, att_dst,
                                                          hb, a_src, a_dst);
    k_count<<<(NEDGES / 4 + 255) / 256, 256, 0, stream>>>(ei, deg, rank);
    k_scan1<<<NB, 256, 0, stream>>>(deg, bsum);
    k_scan2<<<1, 512, 0, stream>>>(bsum, boff);
    k_scan3<<<NB, 256, 0, stream>>>(deg, boff, rowptr, cursor, es);
    k_scatter<<<(NEDGES / 4 + 255) / 256, 256, 0, stream>>>(ei, rowptr, rank, es);
    k_agg<<<NNODES / 4, 256, 0, stream>>>(es, rowptr, cursor, a_src, a_dst,
                                          (const uint2*)hb, bias, out);
}